// Round 11
// baseline (860.716 us; speedup 1.0000x reference)
//
#include <hip/hip_runtime.h>
#include <hip/hip_cooperative_groups.h>

namespace cg = cooperative_groups;

#define NS 64
#define HH 64
#define WW 64
#define VD 64
#define VH 64
#define VW 64
#define NVOX (VD*VH*VW)
#define NPIX (NS*HH*WW)
#define RES 1.5f
#define NTAB (NS*27)
#define WIN 6
#define SPLIT 8
#define COL_PAD 67
#define GP_ROW 68
#define GP_SLC (66*GP_ROW)      // 4488 floats per padded slice
#define GP_TOT (NS*GP_SLC)      // 287232
#define NBLK 512
#define NTHR 512

// ---------------------------------------------------------------
// table entry (16 floats):
//  [0..3]  a,c,b,d   (ws = a*rx + b*ry, hs = c*rx + d*ry)
//  [4..7]  Ux,Uy,Vx,Vy
//  [8..11] Uz,Vz,Cx,Cy
//  [12..15]Cz,psf_k,0,0
// ---------------------------------------------------------------
__device__ __forceinline__ void setup_entry(int i, const float* __restrict__ tr,
                                            const float* __restrict__ psf,
                                            float* __restrict__ tab) {
    int s = i / 27, k = i % 27;
    const float* p = tr + s * 12;
    float R00 = p[0], R01 = p[1], R02 = p[2],  t0 = p[3];
    float R10 = p[4], R11 = p[5], R12 = p[6],  t1 = p[7];
    float R20 = p[8], R21 = p[9], R22 = p[10], t2 = p[11];
    float Ux = RES * R00, Uy = RES * R10, Uz = RES * R20;
    float Vx = RES * R01, Vy = RES * R11, Vz = RES * R21;
    float ox = (float)(k % 3 - 1), oy = (float)((k / 3) % 3 - 1), oz = (float)(k / 9 - 1);
    float Cx = t0 + 31.5f + R00 * ox + R01 * oy + R02 * oz - 31.5f * (Ux + Vx);
    float Cy = t1 + 31.5f + R10 * ox + R11 * oy + R12 * oz - 31.5f * (Uy + Vy);
    float Cz = t2 + 31.5f + R20 * ox + R21 * oy + R22 * oz - 31.5f * (Uz + Vz);
    float inv = 1.f / (Ux * Vy - Uy * Vx);
    float* e = tab + i * 16;
    e[0] = Vy * inv;  e[1] = -Uy * inv;  e[2] = -Vx * inv; e[3] = Ux * inv;
    e[4] = Ux; e[5] = Uy; e[6] = Vx; e[7] = Vy;
    e[8] = Uz; e[9] = Vz; e[10] = Cx; e[11] = Cy;
    e[12] = Cz; e[13] = psf[k]; e[14] = 0.f; e[15] = 0.f;
}

// ---------------------------------------------------------------
// Branch-free trilinear gather (clamped idx, zeroed weights).
// ---------------------------------------------------------------
__device__ __forceinline__ float trilin_gather_bf(const float* __restrict__ vol,
                                                  float px, float py, float pz) {
    float x0 = floorf(px), y0 = floorf(py), z0 = floorf(pz);
    float fx = px - x0, fy = py - y0, fz = pz - z0;
    int ix = (int)x0, iy = (int)y0, iz = (int)z0;

    float wx0 = ((unsigned)ix       < 64u) ? (1.f - fx) : 0.f;
    float wx1 = ((unsigned)(ix + 1) < 64u) ? fx         : 0.f;
    float wy0 = ((unsigned)iy       < 64u) ? (1.f - fy) : 0.f;
    float wy1 = ((unsigned)(iy + 1) < 64u) ? fy         : 0.f;
    float wz0 = ((unsigned)iz       < 64u) ? (1.f - fz) : 0.f;
    float wz1 = ((unsigned)(iz + 1) < 64u) ? fz         : 0.f;

    int xc0 = min(max(ix, 0), 63),     xc1 = min(max(ix + 1, 0), 63);
    int yc0 = min(max(iy, 0), 63) << 6,  yc1 = min(max(iy + 1, 0), 63) << 6;
    int zc0 = min(max(iz, 0), 63) << 12, zc1 = min(max(iz + 1, 0), 63) << 12;

    float v000 = vol[zc0 + yc0 + xc0], v001 = vol[zc0 + yc0 + xc1];
    float v010 = vol[zc0 + yc1 + xc0], v011 = vol[zc0 + yc1 + xc1];
    float v100 = vol[zc1 + yc0 + xc0], v101 = vol[zc1 + yc0 + xc1];
    float v110 = vol[zc1 + yc1 + xc0], v111 = vol[zc1 + yc1 + xc1];

    float w00 = wx0 * wy0, w01 = wx1 * wy0, w10 = wx0 * wy1, w11 = wx1 * wy1;
    float lo = fmaf(w00, v000, fmaf(w01, v001, fmaf(w10, v010, w11 * v011)));
    float hi = fmaf(w00, v100, fmaf(w01, v101, fmaf(w10, v110, w11 * v111)));
    return fmaf(wz0, lo, wz1 * hi);
}

// ---------------------------------------------------------------
// Forward projection A for one pixel (per-tap OOB skip).
// SUB: g = slc - A(vin). Writes zero-padded g.
// ---------------------------------------------------------------
template<bool SUB>
__device__ __forceinline__ void phase_a(const float* __restrict__ vin,
                                        float* __restrict__ gp,
                                        const float* __restrict__ tr,
                                        const float* __restrict__ psf,
                                        const float* __restrict__ slc,
                                        int gid) {
    int s = gid >> 12;
    int h = (gid >> 6) & 63, w = gid & 63;
    const float* p = tr + s * 12;
    float R0 = p[0], R1 = p[1], R2 = p[2],  t0 = p[3];
    float R3 = p[4], R4 = p[5], R5 = p[6],  t1 = p[7];
    float R6 = p[8], R7 = p[9], R8 = p[10], t2 = p[11];
    float xs = ((float)w - 31.5f) * RES;
    float ys = ((float)h - 31.5f) * RES;
    float p0x = fmaf(R0, xs, fmaf(R1, ys, t0)) + 31.5f;
    float p0y = fmaf(R3, xs, fmaf(R4, ys, t1)) + 31.5f;
    float p0z = fmaf(R6, xs, fmaf(R7, ys, t2)) + 31.5f;
    float a = 0.f;
#pragma unroll
    for (int k = 0; k < 27; ++k) {
        const float ox = (float)(k % 3 - 1), oy = (float)((k / 3) % 3 - 1), oz = (float)(k / 9 - 1);
        float px = p0x + ox * R0 + oy * R1 + oz * R2;
        float py = p0y + ox * R3 + oy * R4 + oz * R5;
        float pz = p0z + ox * R6 + oy * R7 + oz * R8;
        bool inb = (px > -1.f) & (px < 64.f) & (py > -1.f) & (py < 64.f)
                 & (pz > -1.f) & (pz < 64.f);
        if (inb) a = fmaf(psf[k], trilin_gather_bf(vin, px, py, pz), a);
    }
    float outv = SUB ? (slc[gid] - a) : a;
    gp[s * GP_SLC + (h + 1) * GP_ROW + (w + 1)] = outv;
}

// ---------------------------------------------------------------
// Adjoint At for one (y-row, split) block: wave-uniform slice,
// 6-slot register z-window, per-column LDS accumulators.
// 512 threads = 8 waves; wave = 64 cols x 1 slice.
// ---------------------------------------------------------------
__device__ __forceinline__ void phase_atv(const float* __restrict__ g,
                                          float* __restrict__ part,
                                          const float* __restrict__ tab,
                                          int bid, int tid,
                                          float cols[64][COL_PAD]) {
    {
        float4* c4 = (float4*)&cols[0][0];   // 64*67=4288 floats = 1072 float4
#pragma unroll
        for (int i = 0; i < 3; ++i) {
            int j = tid + i * 512;
            if (j < 1072) c4[j] = make_float4(0.f, 0.f, 0.f, 0.f);
        }
    }
    __syncthreads();

    int Yb    = bid >> 3;
    int split = bid & 7;
    int lane  = tid & 63;
    int wave  = tid >> 6;
    int s = __builtin_amdgcn_readfirstlane(split * 8 + wave);
    float X = (float)lane, Y = (float)Yb;

    const float* tb = tab + s * 27 * 16;
    int gbase = s * GP_SLC;

    // window base from center tap (k=13)
    const float* ec = tb + 13 * 16;
    float4 ce0 = *(const float4*)(ec);
    float4 ce2 = *(const float4*)(ec + 8);
    float4 ce3 = *(const float4*)(ec + 12);
    float rxc = X - ce2.z, ryc = Y - ce2.w;
    float wsc = ce0.x * rxc + ce0.z * ryc;
    float hsc = ce0.y * rxc + ce0.w * ryc;
    float pzc = fmaf(wsc, ce2.x, fmaf(hsc, ce2.y, ce3.x));
    float basef = floorf(pzc) - 2.f;
    int   basei = (int)basef;

    float acc[WIN];
#pragma unroll
    for (int j = 0; j < WIN; ++j) acc[j] = 0.f;

#pragma unroll 3
    for (int k = 0; k < 27; ++k) {
        const float* e = tb + k * 16;
        float4 e0 = *(const float4*)(e);
        float4 e1 = *(const float4*)(e + 4);
        float4 e2 = *(const float4*)(e + 8);
        float4 e3 = *(const float4*)(e + 12);
        float rx = X - e2.z, ry = Y - e2.w;
        float ws = e0.x * rx + e0.z * ry;
        float hs = e0.y * rx + e0.w * ry;
        float w0f = __builtin_amdgcn_fmed3f(floorf(ws), -1.f, 63.f);
        float h0f = __builtin_amdgcn_fmed3f(floorf(hs), -1.f, 63.f);
        int wA = (int)w0f, hA = (int)h0f;
        float Ux = e1.x, Uy = e1.y, Vx = e1.z, Vy = e1.w;
        float Uz = e2.x, Vz = e2.y;
        float Czb = e3.x - basef;
        float psfk = e3.y;
        float Cxr = -rx, Cyr = -ry;
        int colbase = gbase + wA + 1;
#pragma unroll
        for (int dh = 0; dh < 2; ++dh) {
            float fh = h0f + (float)dh;
            float tx  = fmaf(fh, Vx, Cxr);
            float ty  = fmaf(fh, Vy, Cyr);
            float tzb = fmaf(fh, Vz, Czb);
            int rowoff = colbase + (hA + 1 + dh) * GP_ROW;
#pragma unroll
            for (int dw = 0; dw < 2; ++dw) {
                float fw = w0f + (float)dw;
                float ddx = fmaf(fw, Ux, tx);
                float ddy = fmaf(fw, Uy, ty);
                float wx = fmaxf(1.f - fabsf(ddx), 0.f);
                float wy = fmaxf(1.f - fabsf(ddy), 0.f);
                float gv = g[rowoff + dw];
                float val = wx * wy * psfk * gv;
                float prel = fmaf(fw, Uz, tzb);
#pragma unroll
                for (int j = 0; j < WIN; ++j) {
                    float t = fmaxf(0.f, 1.f - fabsf(prel - (float)j));
                    acc[j] = fmaf(val, t, acc[j]);
                }
            }
        }
    }

#pragma unroll
    for (int j = 0; j < WIN; ++j) {
        int zj = basei + j;
        int okz = ((unsigned)zj < 64u);
        int zc = min(max(zj, 0), 63);
        atomicAdd(&cols[lane][zc], okz ? acc[j] : 0.f);
    }
    __syncthreads();

    float* pout = part + split * NVOX + (Yb << 6);
#pragma unroll
    for (int i = 0; i < 8; ++i) {
        int j = tid + i * 512;
        int z = j >> 6, x = j & 63;
        pout[(z << 12) + x] = cols[x][z];
    }
}

__device__ __forceinline__ float sum8(const float* __restrict__ part, int i) {
    float a = 0.f;
#pragma unroll
    for (int j = 0; j < SPLIT; ++j) a += part[j * NVOX + i];
    return a;
}

// 512-thread block reduce -> one device atomic
__device__ __forceinline__ void bred512(float v, float* dst, float* s_red, int tid) {
#pragma unroll
    for (int off = 32; off > 0; off >>= 1) v += __shfl_down(v, off, 64);
    int lane = tid & 63, wid = tid >> 6;
    if (lane == 0) s_red[wid] = v;
    __syncthreads();
    if (tid == 0) {
        float t = 0.f;
#pragma unroll
        for (int j = 0; j < 8; ++j) t += s_red[j];
        atomicAdd(dst, t);
    }
    __syncthreads();
}

// ---------------------------------------------------------------
// THE MEGAKERNEL: entire CG solve, 13 grid syncs, 1 launch.
// grid = 512 x 512 (= NPIX = NVOX threads, 2 blocks/CU co-resident)
// ---------------------------------------------------------------
__global__ __launch_bounds__(512, 4) void mega(const float* __restrict__ tr,
                                               const float* __restrict__ slices,
                                               const float* __restrict__ volume,
                                               const float* __restrict__ psf,
                                               float* __restrict__ out,
                                               float* tab, float* gbuf, float* scal,
                                               float* part, float* vol_x,
                                               float* vol_r, float* vol_p, float* Ap) {
    cg::grid_group grid = cg::this_grid();
    __shared__ float cols[64][COL_PAD];
    __shared__ float s_red[8];
    int tid = threadIdx.x;
    int bid = blockIdx.x;
    int gidx = bid * NTHR + tid;        // 0 .. 262143

    // P0: table + zero padded-g + scal
    if (gidx < NTAB) setup_entry(gidx, tr, psf, tab);
    for (int i = gidx; i < GP_TOT + 8; i += NBLK * NTHR) gbuf[i] = 0.f;
    grid.sync();

    // P1: g = slices - A(x0)
    phase_a<true>(volume, gbuf, tr, psf, slices, gidx);
    grid.sync();
    // P2: part = At(g)
    phase_atv(gbuf, part, tab, bid, tid, cols);
    grid.sync();
    // P3: r = p = sum8(part); rr0
    {
        float rv = sum8(part, gidx);
        vol_r[gidx] = rv;
        vol_p[gidx] = rv;
        bred512(rv * rv, &scal[0], s_red, tid);
    }
    grid.sync();

    // iter 0
    phase_a<false>(vol_p, gbuf, tr, psf, nullptr, gidx);   // P4
    grid.sync();
    phase_atv(gbuf, part, tab, bid, tid, cols);            // P5
    grid.sync();
    {                                                      // P6: Ap, pAp0
        float apv = sum8(part, gidx);
        Ap[gidx] = apv;
        bred512(vol_p[gidx] * apv, &scal[1], s_red, tid);
    }
    grid.sync();
    {                                                      // P7: x, r, rr1
        float alpha = scal[0] / scal[1];
        vol_x[gidx] = fmaf(alpha, vol_p[gidx], volume[gidx]);
        float rv = fmaf(-alpha, Ap[gidx], vol_r[gidx]);
        vol_r[gidx] = rv;
        bred512(rv * rv, &scal[2], s_red, tid);
    }
    grid.sync();
    {                                                      // P8: p = r + beta p
        float beta = scal[2] / scal[0];
        vol_p[gidx] = fmaf(beta, vol_p[gidx], vol_r[gidx]);
    }
    grid.sync();

    // iter 1
    phase_a<false>(vol_p, gbuf, tr, psf, nullptr, gidx);   // P9
    grid.sync();
    phase_atv(gbuf, part, tab, bid, tid, cols);            // P10
    grid.sync();
    bred512(vol_p[gidx] * sum8(part, gidx), &scal[3], s_red, tid);  // P11
    grid.sync();
    {                                                      // P12: out
        float alpha = scal[2] / scal[3];
        float v = fmaf(alpha, vol_p[gidx], vol_x[gidx]);
        out[gidx] = v > 0.f ? v : 0.f;
    }
}

// ---------------- fallback multi-kernel path (r10) ----------------

__global__ __launch_bounds__(256) void k_setup(const float* __restrict__ tr,
                                               const float* __restrict__ psf,
                                               float* __restrict__ tab) {
    int i = blockIdx.x * 256 + threadIdx.x;
    if (i < NTAB) setup_entry(i, tr, psf, tab);
}

template<bool SUB>
__global__ __launch_bounds__(256) void k_a(const float* __restrict__ vin,
                                           float* __restrict__ gp,
                                           const float* __restrict__ tr,
                                           const float* __restrict__ psf,
                                           const float* __restrict__ slc) {
    phase_a<SUB>(vin, gp, tr, psf, slc, blockIdx.x * 256 + threadIdx.x);
}

__global__ __launch_bounds__(512, 2) void k_atv(const float* __restrict__ g,
                                                float* __restrict__ part,
                                                const float* __restrict__ tab) {
    __shared__ float cols[64][COL_PAD];
    phase_atv(g, part, tab, blockIdx.x, threadIdx.x, cols);
}

__device__ __forceinline__ void bred256(float v, float* dst) {
#pragma unroll
    for (int off = 32; off > 0; off >>= 1) v += __shfl_down(v, off, 64);
    __shared__ float s_red[4];
    int lane = threadIdx.x & 63, wid = threadIdx.x >> 6;
    if (lane == 0) s_red[wid] = v;
    __syncthreads();
    if (threadIdx.x == 0) atomicAdd(dst, s_red[0] + s_red[1] + s_red[2] + s_red[3]);
}

__global__ __launch_bounds__(256) void k_residual8(const float* __restrict__ part,
                                                   float* __restrict__ r,
                                                   float* __restrict__ p,
                                                   float* __restrict__ scal) {
    int i = blockIdx.x * 256 + threadIdx.x;
    float rv = sum8(part, i);
    r[i] = rv; p[i] = rv;
    bred256(rv * rv, &scal[0]);
}

__global__ __launch_bounds__(256) void k_dot_reduce8(const float* __restrict__ part,
                                                     const float* __restrict__ p,
                                                     float* __restrict__ Ap,
                                                     float* __restrict__ dst) {
    int i = blockIdx.x * 256 + threadIdx.x;
    float apv = sum8(part, i);
    Ap[i] = apv;
    bred256(p[i] * apv, dst);
}

__global__ __launch_bounds__(256) void k_dot8(const float* __restrict__ part,
                                              const float* __restrict__ p,
                                              float* __restrict__ dst) {
    int i = blockIdx.x * 256 + threadIdx.x;
    bred256(p[i] * sum8(part, i), dst);
}

__global__ __launch_bounds__(256) void k_update_xr(const float* __restrict__ x_in,
                                                   float* __restrict__ x_out,
                                                   float* __restrict__ r,
                                                   const float* __restrict__ p,
                                                   const float* __restrict__ Ap,
                                                   float* __restrict__ scal) {
    int i = blockIdx.x * 256 + threadIdx.x;
    float alpha = scal[0] / scal[1];
    x_out[i] = fmaf(alpha, p[i], x_in[i]);
    float rv = fmaf(-alpha, Ap[i], r[i]);
    r[i] = rv;
    bred256(rv * rv, &scal[2]);
}

__global__ __launch_bounds__(256) void k_update_p(float* __restrict__ p,
                                                  const float* __restrict__ r,
                                                  const float* __restrict__ scal) {
    int i = blockIdx.x * 256 + threadIdx.x;
    float beta = scal[2] / scal[0];
    p[i] = fmaf(beta, p[i], r[i]);
}

__global__ __launch_bounds__(256) void k_final(const float* __restrict__ x,
                                               const float* __restrict__ p,
                                               const float* __restrict__ scal,
                                               float* __restrict__ out) {
    int i = blockIdx.x * 256 + threadIdx.x;
    float alpha = scal[2] / scal[3];
    float v = fmaf(alpha, p[i], x[i]);
    out[i] = v > 0.f ? v : 0.f;
}

extern "C" void kernel_launch(void* const* d_in, const int* in_sizes, int n_in,
                              void* d_out, int out_size, void* d_ws, size_t ws_size,
                              hipStream_t stream) {
    const float* transforms = (const float*)d_in[0];
    const float* slices     = (const float*)d_in[1];
    const float* volume     = (const float*)d_in[2];
    const float* psf        = (const float*)d_in[3];
    float* out = (float*)d_out;

    float* tab    = (float*)d_ws;             // NTAB*16
    float* gbuf   = tab    + NTAB * 16;       // GP_TOT (zero-padded g)
    float* scal   = gbuf   + GP_TOT;          // 8 floats
    float* part   = scal   + 8;               // 8 * NVOX
    float* vol_x  = part   + SPLIT * NVOX;
    float* vol_r  = vol_x  + NVOX;
    float* vol_p  = vol_r  + NVOX;
    float* Ap     = vol_p  + NVOX;

    void* args[] = {(void*)&transforms, (void*)&slices, (void*)&volume, (void*)&psf,
                    (void*)&out, (void*)&tab, (void*)&gbuf, (void*)&scal, (void*)&part,
                    (void*)&vol_x, (void*)&vol_r, (void*)&vol_p, (void*)&Ap};

    hipError_t err = hipLaunchCooperativeKernel((void*)mega, dim3(NBLK), dim3(NTHR),
                                                args, 0, stream);
    if (err == hipSuccess) return;

    // ---------- fallback: r10 multi-kernel path ----------
    const int ablk = 64 * SPLIT;              // 512
    const int fblk = NPIX / 256;              // 1024
    const int vblk = NVOX / 256;              // 1024

    hipMemsetAsync(gbuf, 0, (GP_TOT + 8) * sizeof(float), stream);
    k_setup<<<(NTAB + 255) / 256, 256, 0, stream>>>(transforms, psf, tab);

    k_a<true><<<fblk, 256, 0, stream>>>(volume, gbuf, transforms, psf, slices);
    k_atv<<<ablk, 512, 0, stream>>>(gbuf, part, tab);
    k_residual8<<<vblk, 256, 0, stream>>>(part, vol_r, vol_p, scal);

    k_a<false><<<fblk, 256, 0, stream>>>(vol_p, gbuf, transforms, psf, nullptr);
    k_atv<<<ablk, 512, 0, stream>>>(gbuf, part, tab);
    k_dot_reduce8<<<vblk, 256, 0, stream>>>(part, vol_p, Ap, &scal[1]);
    k_update_xr<<<vblk, 256, 0, stream>>>(volume, vol_x, vol_r, vol_p, Ap, scal);
    k_update_p<<<vblk, 256, 0, stream>>>(vol_p, vol_r, scal);

    k_a<false><<<fblk, 256, 0, stream>>>(vol_p, gbuf, transforms, psf, nullptr);
    k_atv<<<ablk, 512, 0, stream>>>(gbuf, part, tab);
    k_dot8<<<vblk, 256, 0, stream>>>(part, vol_p, &scal[3]);
    k_final<<<vblk, 256, 0, stream>>>(vol_x, vol_p, scal, out);
}